// Round 6
// baseline (770.922 us; speedup 1.0000x reference)
//
#include <hip/hip_runtime.h>

// ---------------------------------------------------------------------------
// StructuralGNN: GCN -> SAGE -> GAT(2 heads) -> Linear on N=50k, E=1.6M, D=128
// Round 6: gat_gather computes softmax weights lane-parallel (1 exp per 32
// edges instead of per edge) and broadcasts (s,w) via shfl; GEMM stages A
// transposed for contiguous b128 LDS reads. bf16 gather tables kept.
// ---------------------------------------------------------------------------

static __device__ __forceinline__ float leaky02(float x) {
    return x > 0.f ? x : 0.2f * x;
}
static __device__ __forceinline__ unsigned short f2bf(float f) {
    unsigned u = __float_as_uint(f);
    u = (u + 0x7FFFu + ((u >> 16) & 1u)) >> 16;   // RNE
    return (unsigned short)u;
}
static __device__ __forceinline__ float bf2f(unsigned short h) {
    return __uint_as_float(((unsigned)h) << 16);
}
static __device__ __forceinline__ float4 bf4(ushort4 h) {
    return make_float4(bf2f(h.x), bf2f(h.y), bf2f(h.z), bf2f(h.w));
}

// ---------------------------------------------------------------------------
__global__ void deg_edges(const int* __restrict__ dst, int* __restrict__ degi, int E) {
    int e = blockIdx.x * blockDim.x + threadIdx.x;
    if (e < E) atomicAdd(&degi[dst[e]], 1);
}

// per-1024-chunk sums of edge counts + dinv/icnt computation
__global__ __launch_bounds__(256)
void scan_part_norm(const int* __restrict__ degi, int* __restrict__ partial,
                    float* __restrict__ dinv, float* __restrict__ icnt, int n)
{
    int t = threadIdx.x;
    int base = blockIdx.x * 1024 + t * 4;
    int s = 0;
#pragma unroll
    for (int i = 0; i < 4; ++i) {
        int g = base + i;
        if (g < n) {
            int de = degi[g];                    // in-edges (no self)
            s += de;
            dinv[g] = rsqrtf((float)(de + 1));   // GCN deg includes self loop
            icnt[g] = 1.0f / (float)(de > 1 ? de : 1);
        }
    }
#pragma unroll
    for (int m = 32; m > 0; m >>= 1) s += __shfl_xor(s, m, 64);
    __shared__ int wsum[4];
    if ((t & 63) == 0) wsum[t >> 6] = s;
    __syncthreads();
    if (t == 0) partial[blockIdx.x] = wsum[0] + wsum[1] + wsum[2] + wsum[3];
}

// single wave scans chunk sums -> exclusive offsets
__global__ __launch_bounds__(64)
void scan_offsets(int* __restrict__ partial, int nb)
{
    int t = threadIdx.x;
    int carry = 0;
    for (int base = 0; base < nb; base += 64) {
        int i = base + t;
        int v = (i < nb) ? partial[i] : 0;
        int incl = v;
#pragma unroll
        for (int m = 1; m < 64; m <<= 1) {
            int o = __shfl_up(incl, m, 64);
            if (t >= m) incl += o;
        }
        if (i < nb) partial[i] = incl - v + carry;
        carry += __shfl(incl, 63, 64);
    }
}

// per-chunk exclusive scan + chunk offset -> rowptr
__global__ __launch_bounds__(256)
void scan_write(const int* __restrict__ degi, const int* __restrict__ partial,
                int* __restrict__ rowptr, int n)
{
    __shared__ int tmp[256];
    int t = threadIdx.x;
    int base = blockIdx.x * 1024 + t * 4;
    int v[4]; int s = 0;
#pragma unroll
    for (int i = 0; i < 4; ++i) {
        int g = base + i;
        v[i] = (g < n) ? degi[g] : 0;
        s += v[i];
    }
    tmp[t] = s;
    __syncthreads();
    for (int off = 1; off < 256; off <<= 1) {
        int a = (t >= off) ? tmp[t - off] : 0;
        __syncthreads();
        tmp[t] += a;
        __syncthreads();
    }
    int run = tmp[t] - s + partial[blockIdx.x];
#pragma unroll
    for (int i = 0; i < 4; ++i) {
        int g = base + i;
        run += v[i];
        if (g < n) rowptr[g + 1] = run;
    }
    if (blockIdx.x == 0 && t == 0) rowptr[0] = 0;
}

__global__ void csr_fill(const int* __restrict__ src, const int* __restrict__ dst,
                         const int* __restrict__ rowptr, int* __restrict__ fill,
                         int* __restrict__ csr, int E)
{
    int e = blockIdx.x * blockDim.x + threadIdx.x;
    if (e >= E) return;
    int d = dst[e];
    int pos = rowptr[d] + atomicAdd(&fill[d], 1);
    csr[pos] = src[e];
}

// ---------------------------------------------------------------------------
// C[128-row tile x 128-col slice] = act( scale*(A1@W1 + A2[idx]@W2) + bias )
// 256 threads, 8x8 micro-tile. A staged TRANSPOSED (AsT[k][row], pad 129) so
// per-thread a-reads are one contiguous 32B LDS read (16-lane broadcast).
template<bool HAS_A2, bool RELU, bool HAS_BIAS, bool HAS_IDX, bool SCALE,
         bool ATT, bool OUT_BF16>
__global__ __launch_bounds__(256)
void gemm_k128(const float* __restrict__ A1, const float* __restrict__ W1,
               const float* __restrict__ A2, const float* __restrict__ W2,
               const int* __restrict__ idx2, const float* __restrict__ bias,
               const float* __restrict__ scale,
               const float* __restrict__ att_src, const float* __restrict__ att_dst,
               float* __restrict__ a_s, float* __restrict__ a_d,
               float* __restrict__ C, int nrows, int ncW, int ncC)
{
    __shared__ float AsT[32][129];
    __shared__ float Ws[32][128];
    const int t = threadIdx.x;
    const int tc = t & 15;        // 16 col groups * 8 cols
    const int tr = t >> 4;        // 16 row groups * 8 rows
    const int row0 = blockIdx.x * 128;
    const int colOff = blockIdx.y * 128;

    float acc[8][8] = {};

    const int npass = HAS_A2 ? 2 : 1;
    for (int p = 0; p < npass; ++p) {
        const float* A = (p == 0) ? A1 : A2;
        const float* W = (p == 0) ? W1 : W2;
        for (int kt = 0; kt < 4; ++kt) {
#pragma unroll
            for (int i = 0; i < 4; ++i) {       // stage A transposed: 32k x 128r
                int f = i * 256 + t;
                int r = f >> 3, c4 = (f & 7) << 2;
                int row = row0 + r; if (row >= nrows) row = nrows - 1;
                int arow = (p == 1 && HAS_IDX) ? idx2[row] : row;
                float4 v = *(const float4*)(A + (size_t)arow * 128 + kt * 32 + c4);
                AsT[c4 + 0][r] = v.x; AsT[c4 + 1][r] = v.y;
                AsT[c4 + 2][r] = v.z; AsT[c4 + 3][r] = v.w;
            }
#pragma unroll
            for (int i = 0; i < 4; ++i) {       // stage W: 32 x 128
                int f = i * 256 + t;
                int wr = f >> 5, wc4 = (f & 31) << 2;
                *(float4*)&Ws[wr][wc4] =
                    *(const float4*)(W + (size_t)(kt * 32 + wr) * ncW + colOff + wc4);
            }
            __syncthreads();
#pragma unroll
            for (int kk = 0; kk < 32; ++kk) {
                float a[8], w[8];
                const float* ap = &AsT[kk][tr * 8];
                const float* wp = &Ws[kk][tc * 8];
#pragma unroll
                for (int i = 0; i < 8; ++i) a[i] = ap[i];
#pragma unroll
                for (int j = 0; j < 8; ++j) w[j] = wp[j];
#pragma unroll
                for (int i = 0; i < 8; ++i)
#pragma unroll
                    for (int j = 0; j < 8; ++j)
                        acc[i][j] = fmaf(a[i], w[j], acc[i][j]);
            }
            __syncthreads();
        }
    }

    float as_v[8], ad_v[8];
    if (ATT) {
#pragma unroll
        for (int j = 0; j < 8; ++j) {
            as_v[j] = att_src[colOff + tc * 8 + j];
            ad_v[j] = att_dst[colOff + tc * 8 + j];
        }
    }
#pragma unroll
    for (int i = 0; i < 8; ++i) {
        int row = row0 + tr * 8 + i;
        bool ok = row < nrows;
        float sc = 1.f;
        if (SCALE) sc = ok ? scale[row] : 0.f;
        float vv[8];
#pragma unroll
        for (int j = 0; j < 8; ++j) {
            float v = acc[i][j];
            if (SCALE) v *= sc;
            if (HAS_BIAS) v += bias[colOff + tc * 8 + j];
            if (RELU) v = fmaxf(v, 0.f);
            vv[j] = v;
        }
        if (ok) {
            if (OUT_BF16) {
                unsigned short* cp =
                    (unsigned short*)C + (size_t)row * ncC + colOff + tc * 8;
                uint4 pk;
                pk.x = (unsigned)f2bf(vv[0]) | ((unsigned)f2bf(vv[1]) << 16);
                pk.y = (unsigned)f2bf(vv[2]) | ((unsigned)f2bf(vv[3]) << 16);
                pk.z = (unsigned)f2bf(vv[4]) | ((unsigned)f2bf(vv[5]) << 16);
                pk.w = (unsigned)f2bf(vv[6]) | ((unsigned)f2bf(vv[7]) << 16);
                *(uint4*)cp = pk;
            } else {
                float* cp = C + (size_t)row * ncC + colOff + tc * 8;
                *(float4*)cp = make_float4(vv[0], vv[1], vv[2], vv[3]);
                *(float4*)(cp + 4) = make_float4(vv[4], vv[5], vv[6], vv[7]);
            }
        }
        if (ATT) {
            float ps = 0.f, pd = 0.f;
#pragma unroll
            for (int j = 0; j < 8; ++j) {
                ps = fmaf(vv[j], as_v[j], ps);
                pd = fmaf(vv[j], ad_v[j], pd);
            }
#pragma unroll
            for (int m = 1; m < 16; m <<= 1) {
                ps += __shfl_xor(ps, m, 64);
                pd += __shfl_xor(pd, m, 64);
            }
            if (ok && tc == 0) {
                a_s[row * 2 + blockIdx.y] = ps;
                a_d[row * 2 + blockIdx.y] = pd;
            }
        }
    }
}

// ---------------------------------------------------------------------------
// GCN gather over bf16 hWs (pre-scaled by dinv[src]). Paired edges: lanes
// 0-31 even edges, 32-63 odd; combine via shfl_xor(32).
// h1[d] = relu(dinv[d]*(sum_s hWs[s] + hWs[d]) + b); writes fp32 + bf16 copy.
__global__ __launch_bounds__(256)
void gcn_gather(const int* __restrict__ rowptr, const int* __restrict__ csr,
                const float* __restrict__ dinv,
                const unsigned short* __restrict__ hWb,
                const float* __restrict__ b, float* __restrict__ h1,
                unsigned short* __restrict__ h1b, int n)
{
    int d = blockIdx.x * 4 + (threadIdx.x >> 6);
    if (d >= n) return;
    int lane = threadIdx.x & 63;
    int half = lane >> 5;
    int c = (lane & 31) << 2;      // column group (4 elems)
    int r0 = rowptr[d], r1 = rowptr[d + 1];
    float4 acc = make_float4(0.f, 0.f, 0.f, 0.f);
    int j = r0 + half;
    for (; j + 6 < r1; j += 8) {
        int s0 = csr[j], s1 = csr[j + 2], s2 = csr[j + 4], s3 = csr[j + 6];
        float4 v0 = bf4(*(const ushort4*)(hWb + (size_t)s0 * 128 + c));
        float4 v1 = bf4(*(const ushort4*)(hWb + (size_t)s1 * 128 + c));
        float4 v2 = bf4(*(const ushort4*)(hWb + (size_t)s2 * 128 + c));
        float4 v3 = bf4(*(const ushort4*)(hWb + (size_t)s3 * 128 + c));
        acc.x += (v0.x + v1.x) + (v2.x + v3.x);
        acc.y += (v0.y + v1.y) + (v2.y + v3.y);
        acc.z += (v0.z + v1.z) + (v2.z + v3.z);
        acc.w += (v0.w + v1.w) + (v2.w + v3.w);
    }
    for (; j < r1; j += 2) {
        int s = csr[j];
        float4 v = bf4(*(const ushort4*)(hWb + (size_t)s * 128 + c));
        acc.x += v.x; acc.y += v.y; acc.z += v.z; acc.w += v.w;
    }
    acc.x += __shfl_xor(acc.x, 32, 64);
    acc.y += __shfl_xor(acc.y, 32, 64);
    acc.z += __shfl_xor(acc.z, 32, 64);
    acc.w += __shfl_xor(acc.w, 32, 64);
    if (lane < 32) {
        float dd = dinv[d];
        float4 vd = bf4(*(const ushort4*)(hWb + (size_t)d * 128 + c));
        float4 bb = *(const float4*)(b + c);
        float4 o;
        o.x = fmaxf(fmaf(acc.x + vd.x, dd, bb.x), 0.f);
        o.y = fmaxf(fmaf(acc.y + vd.y, dd, bb.y), 0.f);
        o.z = fmaxf(fmaf(acc.z + vd.z, dd, bb.z), 0.f);
        o.w = fmaxf(fmaf(acc.w + vd.w, dd, bb.w), 0.f);
        *(float4*)(h1 + (size_t)d * 128 + c) = o;
        ushort4 p;
        p.x = f2bf(o.x); p.y = f2bf(o.y); p.z = f2bf(o.z); p.w = f2bf(o.w);
        *(ushort4*)(h1b + (size_t)d * 128 + c) = p;
    }
}

// SAGE gather over bf16 h1: mean[d] = (sum_s h1[s]) * icnt[d]  (fp32 out)
__global__ __launch_bounds__(256)
void sage_gather(const int* __restrict__ rowptr, const int* __restrict__ csr,
                 const float* __restrict__ icnt,
                 const unsigned short* __restrict__ h1b,
                 float* __restrict__ mean, int n)
{
    int d = blockIdx.x * 4 + (threadIdx.x >> 6);
    if (d >= n) return;
    int lane = threadIdx.x & 63;
    int half = lane >> 5;
    int c = (lane & 31) << 2;
    int r0 = rowptr[d], r1 = rowptr[d + 1];
    float4 acc = make_float4(0.f, 0.f, 0.f, 0.f);
    int j = r0 + half;
    for (; j + 6 < r1; j += 8) {
        int s0 = csr[j], s1 = csr[j + 2], s2 = csr[j + 4], s3 = csr[j + 6];
        float4 v0 = bf4(*(const ushort4*)(h1b + (size_t)s0 * 128 + c));
        float4 v1 = bf4(*(const ushort4*)(h1b + (size_t)s1 * 128 + c));
        float4 v2 = bf4(*(const ushort4*)(h1b + (size_t)s2 * 128 + c));
        float4 v3 = bf4(*(const ushort4*)(h1b + (size_t)s3 * 128 + c));
        acc.x += (v0.x + v1.x) + (v2.x + v3.x);
        acc.y += (v0.y + v1.y) + (v2.y + v3.y);
        acc.z += (v0.z + v1.z) + (v2.z + v3.z);
        acc.w += (v0.w + v1.w) + (v2.w + v3.w);
    }
    for (; j < r1; j += 2) {
        int s = csr[j];
        float4 v = bf4(*(const ushort4*)(h1b + (size_t)s * 128 + c));
        acc.x += v.x; acc.y += v.y; acc.z += v.z; acc.w += v.w;
    }
    acc.x += __shfl_xor(acc.x, 32, 64);
    acc.y += __shfl_xor(acc.y, 32, 64);
    acc.z += __shfl_xor(acc.z, 32, 64);
    acc.w += __shfl_xor(acc.w, 32, 64);
    if (lane < 32) {
        float ic = icnt[d];
        float4 o;
        o.x = acc.x * ic; o.y = acc.y * ic; o.z = acc.z * ic; o.w = acc.w * ic;
        *(float4*)(mean + (size_t)d * 128 + c) = o;
    }
}

// ---------------------------------------------------------------------------
// GAT fused single pass, lane-parallel softmax weights:
// per 32-edge block, lane (l&31) computes w = exp(leaky(logit)) for ONE edge
// and head (l>=32); gather loop broadcasts (s,w) via shfl (LDS pipe, no VALU
// exp per edge). wsum accumulated per lane, reduced once at the end.
// Then head-mean + bias + relu + fused out = h3 @ W_out + b_out.
__global__ __launch_bounds__(256)
void gat_gather(const int* __restrict__ rowptr, const int* __restrict__ csr,
                const float* __restrict__ a_s, const float* __restrict__ a_d,
                const unsigned short* __restrict__ xWb,
                const float* __restrict__ b_gat,
                const float* __restrict__ W_out, const float* __restrict__ b_out,
                float* __restrict__ out, int n)
{
    __shared__ float h3row[4][128];
    int wv = threadIdx.x >> 6;
    int d = blockIdx.x * 4 + wv;
    if (d >= n) return;
    int lane = threadIdx.x & 63;
    const int hoff = lane >> 5;          // head for this lane's half
    const int hsel = lane & 32;
    int r0 = rowptr[d], r1 = rowptr[d + 1];
    const int nE = r1 - r0;
    const float adh = a_d[d * 2 + hoff];

    float4 acc = make_float4(0.f, 0.f, 0.f, 0.f);
    float wacc = 0.f;

    for (int blk = 0; blk < nE; blk += 32) {
        int eidx = blk + (lane & 31);
        int s_l = d;
        float wl = 0.f;
        if (eidx < nE) {
            s_l = csr[r0 + eidx];
            wl = __expf(leaky02(a_s[s_l * 2 + hoff] + adh));
        }
        wacc += wl;
        int cnt = min(32, nE - blk);
        int e = 0;
        for (; e + 4 <= cnt; e += 4) {
            int   s0 = __shfl(s_l, e + 0, 64), s1 = __shfl(s_l, e + 1, 64);
            int   s2 = __shfl(s_l, e + 2, 64), s3 = __shfl(s_l, e + 3, 64);
            float w0 = __shfl(wl, (e + 0) | hsel, 64);
            float w1 = __shfl(wl, (e + 1) | hsel, 64);
            float w2 = __shfl(wl, (e + 2) | hsel, 64);
            float w3 = __shfl(wl, (e + 3) | hsel, 64);
            float4 v0 = bf4(((const ushort4*)(xWb + (size_t)s0 * 256))[lane]);
            float4 v1 = bf4(((const ushort4*)(xWb + (size_t)s1 * 256))[lane]);
            float4 v2 = bf4(((const ushort4*)(xWb + (size_t)s2 * 256))[lane]);
            float4 v3 = bf4(((const ushort4*)(xWb + (size_t)s3 * 256))[lane]);
            acc.x = fmaf(v0.x, w0, fmaf(v1.x, w1, fmaf(v2.x, w2, fmaf(v3.x, w3, acc.x))));
            acc.y = fmaf(v0.y, w0, fmaf(v1.y, w1, fmaf(v2.y, w2, fmaf(v3.y, w3, acc.y))));
            acc.z = fmaf(v0.z, w0, fmaf(v1.z, w1, fmaf(v2.z, w2, fmaf(v3.z, w3, acc.z))));
            acc.w = fmaf(v0.w, w0, fmaf(v1.w, w1, fmaf(v2.w, w2, fmaf(v3.w, w3, acc.w))));
        }
        for (; e < cnt; ++e) {
            int   s = __shfl(s_l, e, 64);
            float w = __shfl(wl, e | hsel, 64);
            float4 v = bf4(((const ushort4*)(xWb + (size_t)s * 256))[lane]);
            acc.x = fmaf(v.x, w, acc.x);
            acc.y = fmaf(v.y, w, acc.y);
            acc.z = fmaf(v.z, w, acc.z);
            acc.w = fmaf(v.w, w, acc.w);
        }
    }

    // self loop
    float wself = __expf(leaky02(a_s[d * 2 + hoff] + adh));
    {
        float4 v = bf4(((const ushort4*)(xWb + (size_t)d * 256))[lane]);
        acc.x = fmaf(v.x, wself, acc.x);
        acc.y = fmaf(v.y, wself, acc.y);
        acc.z = fmaf(v.z, wself, acc.z);
        acc.w = fmaf(v.w, wself, acc.w);
    }
    // reduce wsum within each 32-lane half (masks 1..16 stay in-half)
#pragma unroll
    for (int sh = 16; sh > 0; sh >>= 1) wacc += __shfl_xor(wacc, sh, 64);
    float inv = 1.f / (wacc + wself + 1e-16f);
    acc.x *= inv; acc.y *= inv; acc.z *= inv; acc.w *= inv;

    // head-mean + bias + relu -> h3 row in LDS
    float c0 = acc.x + __shfl_xor(acc.x, 32, 64);
    float c1 = acc.y + __shfl_xor(acc.y, 32, 64);
    float c2 = acc.z + __shfl_xor(acc.z, 32, 64);
    float c3 = acc.w + __shfl_xor(acc.w, 32, 64);
    if (lane < 32) {
        float4 bb = ((const float4*)b_gat)[lane];
        float4 o;
        o.x = fmaxf(0.5f * c0 + bb.x, 0.f);
        o.y = fmaxf(0.5f * c1 + bb.y, 0.f);
        o.z = fmaxf(0.5f * c2 + bb.z, 0.f);
        o.w = fmaxf(0.5f * c3 + bb.w, 0.f);
        ((float4*)h3row[wv])[lane] = o;
    }
    __threadfence_block();
    // fused out layer: out[d, lane] = <h3row, W_out[:,lane]> + b_out[lane]
    const float* hr = h3row[wv];
    float t0 = 0.f, t1 = 0.f, t2 = 0.f, t3 = 0.f;
#pragma unroll 8
    for (int k = 0; k < 128; k += 4) {
        t0 = fmaf(hr[k + 0], W_out[(k + 0) * 64 + lane], t0);
        t1 = fmaf(hr[k + 1], W_out[(k + 1) * 64 + lane], t1);
        t2 = fmaf(hr[k + 2], W_out[(k + 2) * 64 + lane], t2);
        t3 = fmaf(hr[k + 3], W_out[(k + 3) * 64 + lane], t3);
    }
    out[(size_t)d * 64 + lane] = (t0 + t1) + (t2 + t3) + b_out[lane];
}

// ---------------------------------------------------------------------------
extern "C" void kernel_launch(void* const* d_in, const int* in_sizes, int n_in,
                              void* d_out, int out_size, void* d_ws, size_t ws_size,
                              hipStream_t stream)
{
    const float* x      = (const float*)d_in[0];
    const int*   ei     = (const int*)d_in[1];
    const int*   nidx   = (const int*)d_in[2];
    const float* emb    = (const float*)d_in[3];
    const float* W_gcn  = (const float*)d_in[4];
    const float* b_gcn  = (const float*)d_in[5];
    const float* W_sl   = (const float*)d_in[6];
    const float* W_sr   = (const float*)d_in[7];
    const float* b_sage = (const float*)d_in[8];
    const float* W_gat  = (const float*)d_in[9];
    const float* att_s  = (const float*)d_in[10];
    const float* att_d  = (const float*)d_in[11];
    const float* b_gat  = (const float*)d_in[12];
    const float* W_out  = (const float*)d_in[13];
    const float* b_out  = (const float*)d_in[14];
    float* out = (float*)d_out;

    const int n = in_sizes[0] / 128;
    const int E = in_sizes[1] / 2;
    const int* esrc = ei;
    const int* edst = ei + E;

    const size_t P = (size_t)n * 128;
    const int nb_scan = (n + 1023) / 1024;
    float* ws   = (float*)d_ws;
    float* mean = ws;                 // P fp32 (SAGE GEMM A1)
    float* h1   = ws + P;             // P fp32 (SAGE GEMM A2)
    float* h2   = ws + 2 * P;         // P fp32 (GAT GEMM A1)
    unsigned short* hWb = (unsigned short*)(ws + 3 * P);          // P bf16
    unsigned short* h1b = (unsigned short*)(ws + 3 * P + P / 2);  // P bf16
    unsigned short* xWb = (unsigned short*)(ws + 4 * P);          // 2P bf16
    float* dinv = ws + 5 * P;         // n
    float* icnt = dinv + n;           // n
    float* a_s  = icnt + n;           // 2n
    float* a_d  = a_s + 2 * n;        // 2n
    int* degi   = (int*)(a_d + 2 * n);// n  \ zeroed by one memset
    int* fill   = degi + n;           // n  /
    int* rowptr = fill + n;           // n+1
    int* partial= rowptr + n + 1;     // nb_scan
    int* csr    = partial + nb_scan + 1;  // E

    const int TB = 256;
    int nblk_e     = (E + TB - 1) / TB;
    int nblk_wav_n = (n + 3) / 4;
    int gemm_rows  = (n + 127) / 128;

    // --- degrees + CSR build ---
    hipMemsetAsync(degi, 0, 2 * (size_t)n * sizeof(int), stream);   // degi+fill
    deg_edges<<<nblk_e, TB, 0, stream>>>(edst, degi, E);
    scan_part_norm<<<nb_scan, TB, 0, stream>>>(degi, partial, dinv, icnt, n);
    scan_offsets<<<1, 64, 0, stream>>>(partial, nb_scan);
    scan_write<<<nb_scan, TB, 0, stream>>>(degi, partial, rowptr, n);
    csr_fill<<<nblk_e, TB, 0, stream>>>(esrc, edst, rowptr, fill, csr, E);

    // --- GCN: hWb = bf16( (x@Wg_top + emb@Wg_bot) * dinv[row] ) ---
    gemm_k128<true, false, false, true, true, false, true>
        <<<dim3(gemm_rows, 1), TB, 0, stream>>>(
        x, W_gcn, emb, W_gcn + 128 * 128, nidx, nullptr, dinv,
        nullptr, nullptr, nullptr, nullptr, (float*)hWb, n, 128, 128);
    gcn_gather<<<nblk_wav_n, TB, 0, stream>>>(rowptr, csr, dinv, hWb, b_gcn,
                                              h1, h1b, n);

    // --- SAGE ---
    sage_gather<<<nblk_wav_n, TB, 0, stream>>>(rowptr, csr, icnt, h1b, mean, n);
    gemm_k128<true, true, true, false, false, false, false>
        <<<dim3(gemm_rows, 1), TB, 0, stream>>>(
        mean, W_sl, h1, W_sr, nullptr, b_sage, nullptr,
        nullptr, nullptr, nullptr, nullptr, h2, n, 128, 128);

    // --- GAT: xWb (bf16) + fused attention logits ---
    gemm_k128<false, false, false, false, false, true, true>
        <<<dim3(gemm_rows, 2), TB, 0, stream>>>(
        h2, W_gat, nullptr, nullptr, nullptr, nullptr, nullptr,
        att_s, att_d, a_s, a_d, (float*)xWb, n, 256, 256);
    gat_gather<<<nblk_wav_n, TB, 0, stream>>>(rowptr, csr, a_s, a_d, xWb, b_gat,
                                              W_out, b_out, out, n);
}

// Round 7
// 604.821 us; speedup vs baseline: 1.2746x; 1.2746x over previous
//
#include <hip/hip_runtime.h>

// ---------------------------------------------------------------------------
// StructuralGNN: GCN -> SAGE -> GAT(2 heads) -> Linear on N=50k, E=1.6M, D=128
// Round 7: GEMMs moved to MFMA (bf16 split-precision, 3-product compensation:
// A*W ~ ah*bh + ah*bl + al*bh, rel err ~2^-17). LDS holds fragments in
// lane-contiguous order -> conflict-free ds_read_b128. Gathers unchanged
// (round-6 lane-parallel gat_gather, bf16 tables).
// ---------------------------------------------------------------------------

typedef short bf16x8 __attribute__((ext_vector_type(8)));
typedef float f32x4  __attribute__((ext_vector_type(4)));

static __device__ __forceinline__ float leaky02(float x) {
    return x > 0.f ? x : 0.2f * x;
}
static __device__ __forceinline__ unsigned short f2bf(float f) {
    unsigned u = __float_as_uint(f);
    u = (u + 0x7FFFu + ((u >> 16) & 1u)) >> 16;   // RNE
    return (unsigned short)u;
}
static __device__ __forceinline__ float bf2f(unsigned short h) {
    return __uint_as_float(((unsigned)h) << 16);
}
static __device__ __forceinline__ float4 bf4(ushort4 h) {
    return make_float4(bf2f(h.x), bf2f(h.y), bf2f(h.z), bf2f(h.w));
}
// split v into hi (truncated bf16) + lo (bf16 of remainder); hi+lo ~ v (2^-17)
static __device__ __forceinline__ void split_bf(float v, unsigned short& h,
                                                unsigned short& l) {
    unsigned u = __float_as_uint(v);
    unsigned uh = u & 0xFFFF0000u;
    h = (unsigned short)(uh >> 16);
    l = f2bf(v - __uint_as_float(uh));
}

// ---------------------------------------------------------------------------
__global__ void deg_edges(const int* __restrict__ dst, int* __restrict__ degi, int E) {
    int e = blockIdx.x * blockDim.x + threadIdx.x;
    if (e < E) atomicAdd(&degi[dst[e]], 1);
}

__global__ __launch_bounds__(256)
void scan_part_norm(const int* __restrict__ degi, int* __restrict__ partial,
                    float* __restrict__ dinv, float* __restrict__ icnt, int n)
{
    int t = threadIdx.x;
    int base = blockIdx.x * 1024 + t * 4;
    int s = 0;
#pragma unroll
    for (int i = 0; i < 4; ++i) {
        int g = base + i;
        if (g < n) {
            int de = degi[g];
            s += de;
            dinv[g] = rsqrtf((float)(de + 1));
            icnt[g] = 1.0f / (float)(de > 1 ? de : 1);
        }
    }
#pragma unroll
    for (int m = 32; m > 0; m >>= 1) s += __shfl_xor(s, m, 64);
    __shared__ int wsum[4];
    if ((t & 63) == 0) wsum[t >> 6] = s;
    __syncthreads();
    if (t == 0) partial[blockIdx.x] = wsum[0] + wsum[1] + wsum[2] + wsum[3];
}

__global__ __launch_bounds__(64)
void scan_offsets(int* __restrict__ partial, int nb)
{
    int t = threadIdx.x;
    int carry = 0;
    for (int base = 0; base < nb; base += 64) {
        int i = base + t;
        int v = (i < nb) ? partial[i] : 0;
        int incl = v;
#pragma unroll
        for (int m = 1; m < 64; m <<= 1) {
            int o = __shfl_up(incl, m, 64);
            if (t >= m) incl += o;
        }
        if (i < nb) partial[i] = incl - v + carry;
        carry += __shfl(incl, 63, 64);
    }
}

__global__ __launch_bounds__(256)
void scan_write(const int* __restrict__ degi, const int* __restrict__ partial,
                int* __restrict__ rowptr, int n)
{
    __shared__ int tmp[256];
    int t = threadIdx.x;
    int base = blockIdx.x * 1024 + t * 4;
    int v[4]; int s = 0;
#pragma unroll
    for (int i = 0; i < 4; ++i) {
        int g = base + i;
        v[i] = (g < n) ? degi[g] : 0;
        s += v[i];
    }
    tmp[t] = s;
    __syncthreads();
    for (int off = 1; off < 256; off <<= 1) {
        int a = (t >= off) ? tmp[t - off] : 0;
        __syncthreads();
        tmp[t] += a;
        __syncthreads();
    }
    int run = tmp[t] - s + partial[blockIdx.x];
#pragma unroll
    for (int i = 0; i < 4; ++i) {
        int g = base + i;
        run += v[i];
        if (g < n) rowptr[g + 1] = run;
    }
    if (blockIdx.x == 0 && t == 0) rowptr[0] = 0;
}

__global__ void csr_fill(const int* __restrict__ src, const int* __restrict__ dst,
                         const int* __restrict__ rowptr, int* __restrict__ fill,
                         int* __restrict__ csr, int E)
{
    int e = blockIdx.x * blockDim.x + threadIdx.x;
    if (e >= E) return;
    int d = dst[e];
    int pos = rowptr[d] + atomicAdd(&fill[d], 1);
    csr[pos] = src[e];
}

// ---------------------------------------------------------------------------
// MFMA GEMM: C[128-rows x 128-col slice] = act(scale*(A1@W1 + A2[idx]@W2)+bias)
// 256 threads = 4 waves; wave computes 32 rows x 128 cols via 2x8 16x16 tiles.
// Split-bf16: 3 MFMA per tile per k-step. LDS fragment-order: lane l's 8
// k-values contiguous -> conflict-free b128 reads.
// Fragment maps (m89-verified family): A row=l&15, k=(l>>4)*8+j;
// B col=l&15, k=(l>>4)*8+j; D col=l&15, row=(l>>4)*4+reg.
template<bool HAS_A2, bool RELU, bool HAS_BIAS, bool HAS_IDX, bool SCALE,
         bool ATT, bool OUT_BF16>
__global__ __launch_bounds__(256)
void gemm_mfma(const float* __restrict__ A1, const float* __restrict__ W1,
               const float* __restrict__ A2, const float* __restrict__ W2,
               const int* __restrict__ idx2, const float* __restrict__ bias,
               const float* __restrict__ scale,
               const float* __restrict__ att_src, const float* __restrict__ att_dst,
               float* __restrict__ a_s, float* __restrict__ a_d,
               float* __restrict__ C, int nrows, int ncW, int ncC)
{
    __shared__ unsigned short ABh[8][65][8], ABl[8][65][8];
    __shared__ unsigned short WBh[8][65][8], WBl[8][65][8];
    const int t    = threadIdx.x;
    const int lane = t & 63;
    const int wv   = t >> 6;
    const int l15  = lane & 15;
    const int lg   = lane >> 4;
    const int row0 = blockIdx.x * 128;
    const int colOff = blockIdx.y * 128;

    f32x4 acc[2][8];
#pragma unroll
    for (int mt = 0; mt < 2; ++mt)
#pragma unroll
        for (int nt = 0; nt < 8; ++nt) acc[mt][nt] = (f32x4){0.f, 0.f, 0.f, 0.f};

    const int npass = HAS_A2 ? 2 : 1;
    for (int p = 0; p < npass; ++p) {
        const float* A = (p == 0) ? A1 : A2;
        const float* W = (p == 0) ? W1 : W2;
        for (int kt = 0; kt < 4; ++kt) {
            // ---- stage A: 128 rows x 32 k ----
#pragma unroll
            for (int i = 0; i < 4; ++i) {
                int f = i * 256 + t;
                int r = f >> 3, c4 = (f & 7) << 2;
                int row = row0 + r; if (row >= nrows) row = nrows - 1;
                int arow = (p == 1 && HAS_IDX) ? idx2[row] : row;
                float4 v = *(const float4*)(A + (size_t)arow * 128 + kt * 32 + c4);
                int rg = r >> 4;
                int slot = (r & 15) + ((c4 >> 3) << 4);
                int joff = c4 & 4;
                unsigned short h0,l0,h1,l1,h2,l2,h3,l3;
                split_bf(v.x, h0, l0); split_bf(v.y, h1, l1);
                split_bf(v.z, h2, l2); split_bf(v.w, h3, l3);
                *(ushort4*)&ABh[rg][slot][joff] = make_ushort4(h0, h1, h2, h3);
                *(ushort4*)&ABl[rg][slot][joff] = make_ushort4(l0, l1, l2, l3);
            }
            // ---- stage W: 32 k x 128 n ----
#pragma unroll
            for (int i = 0; i < 4; ++i) {
                int f = i * 256 + t;
                int wr = f >> 5, wc4 = (f & 31) << 2;
                float4 v = *(const float4*)(W + (size_t)(kt * 32 + wr) * ncW + colOff + wc4);
                int jj = wr & 7, kg16 = (wr >> 3) << 4;
                int nt = wc4 >> 4, sb = (wc4 & 15) + kg16;
                unsigned short h, l;
                split_bf(v.x, h, l); WBh[nt][sb + 0][jj] = h; WBl[nt][sb + 0][jj] = l;
                split_bf(v.y, h, l); WBh[nt][sb + 1][jj] = h; WBl[nt][sb + 1][jj] = l;
                split_bf(v.z, h, l); WBh[nt][sb + 2][jj] = h; WBl[nt][sb + 2][jj] = l;
                split_bf(v.w, h, l); WBh[nt][sb + 3][jj] = h; WBl[nt][sb + 3][jj] = l;
            }
            __syncthreads();
            // ---- MFMA: 2 m-tiles x 8 n-tiles x 3 products ----
            bf16x8 ah0 = *reinterpret_cast<const bf16x8*>(&ABh[wv * 2 + 0][lane][0]);
            bf16x8 al0 = *reinterpret_cast<const bf16x8*>(&ABl[wv * 2 + 0][lane][0]);
            bf16x8 ah1 = *reinterpret_cast<const bf16x8*>(&ABh[wv * 2 + 1][lane][0]);
            bf16x8 al1 = *reinterpret_cast<const bf16x8*>(&ABl[wv * 2 + 1][lane][0]);
#pragma unroll
            for (int nt = 0; nt < 8; ++nt) {
                bf16x8 bh = *reinterpret_cast<const bf16x8*>(&WBh[nt][lane][0]);
                bf16x8 bl = *reinterpret_cast<const bf16x8*>(&WBl[nt][lane][0]);
                acc[0][nt] = __builtin_amdgcn_mfma_f32_16x16x32_bf16(al0, bh, acc[0][nt], 0, 0, 0);
                acc[0][nt] = __builtin_amdgcn_mfma_f32_16x16x32_bf16(ah0, bl, acc[0][nt], 0, 0, 0);
                acc[0][nt] = __builtin_amdgcn_mfma_f32_16x16x32_bf16(ah0, bh, acc[0][nt], 0, 0, 0);
                acc[1][nt] = __builtin_amdgcn_mfma_f32_16x16x32_bf16(al1, bh, acc[1][nt], 0, 0, 0);
                acc[1][nt] = __builtin_amdgcn_mfma_f32_16x16x32_bf16(ah1, bl, acc[1][nt], 0, 0, 0);
                acc[1][nt] = __builtin_amdgcn_mfma_f32_16x16x32_bf16(ah1, bh, acc[1][nt], 0, 0, 0);
            }
            __syncthreads();
        }
    }

    // ---- epilogue (D layout: col=l15, row=lg*4+reg) ----
    float bias_v[8], as_v[8], ad_v[8];
#pragma unroll
    for (int nt = 0; nt < 8; ++nt) {
        int col = colOff + nt * 16 + l15;
        if (HAS_BIAS) bias_v[nt] = bias[col];
        if (ATT) { as_v[nt] = att_src[col]; ad_v[nt] = att_dst[col]; }
    }
#pragma unroll
    for (int mt = 0; mt < 2; ++mt) {
#pragma unroll
        for (int reg = 0; reg < 4; ++reg) {
            int row = row0 + wv * 32 + mt * 16 + lg * 4 + reg;
            bool ok = row < nrows;
            float sc = 1.f;
            if (SCALE) sc = ok ? scale[row] : 0.f;
            float vv[8];
            float ps = 0.f, pd = 0.f;
#pragma unroll
            for (int nt = 0; nt < 8; ++nt) {
                float v = acc[mt][nt][reg];
                if (SCALE) v *= sc;
                if (HAS_BIAS) v += bias_v[nt];
                if (RELU) v = fmaxf(v, 0.f);
                vv[nt] = v;
                if (ATT) { ps = fmaf(v, as_v[nt], ps); pd = fmaf(v, ad_v[nt], pd); }
            }
            if (ok) {
                if (OUT_BF16) {
                    unsigned short* cp =
                        (unsigned short*)C + (size_t)row * ncC + colOff + l15;
#pragma unroll
                    for (int nt = 0; nt < 8; ++nt) cp[nt * 16] = f2bf(vv[nt]);
                } else {
                    float* cp = C + (size_t)row * ncC + colOff + l15;
#pragma unroll
                    for (int nt = 0; nt < 8; ++nt) cp[nt * 16] = vv[nt];
                }
            }
            if (ATT) {
#pragma unroll
                for (int m = 1; m < 16; m <<= 1) {
                    ps += __shfl_xor(ps, m, 64);
                    pd += __shfl_xor(pd, m, 64);
                }
                if (ok && l15 == 0) {
                    a_s[row * 2 + blockIdx.y] = ps;
                    a_d[row * 2 + blockIdx.y] = pd;
                }
            }
        }
    }
}

// ---------------------------------------------------------------------------
// GCN gather over bf16 hWs (pre-scaled by dinv[src]).
__global__ __launch_bounds__(256)
void gcn_gather(const int* __restrict__ rowptr, const int* __restrict__ csr,
                const float* __restrict__ dinv,
                const unsigned short* __restrict__ hWb,
                const float* __restrict__ b, float* __restrict__ h1,
                unsigned short* __restrict__ h1b, int n)
{
    int d = blockIdx.x * 4 + (threadIdx.x >> 6);
    if (d >= n) return;
    int lane = threadIdx.x & 63;
    int half = lane >> 5;
    int c = (lane & 31) << 2;
    int r0 = rowptr[d], r1 = rowptr[d + 1];
    float4 acc = make_float4(0.f, 0.f, 0.f, 0.f);
    int j = r0 + half;
    for (; j + 6 < r1; j += 8) {
        int s0 = csr[j], s1 = csr[j + 2], s2 = csr[j + 4], s3 = csr[j + 6];
        float4 v0 = bf4(*(const ushort4*)(hWb + (size_t)s0 * 128 + c));
        float4 v1 = bf4(*(const ushort4*)(hWb + (size_t)s1 * 128 + c));
        float4 v2 = bf4(*(const ushort4*)(hWb + (size_t)s2 * 128 + c));
        float4 v3 = bf4(*(const ushort4*)(hWb + (size_t)s3 * 128 + c));
        acc.x += (v0.x + v1.x) + (v2.x + v3.x);
        acc.y += (v0.y + v1.y) + (v2.y + v3.y);
        acc.z += (v0.z + v1.z) + (v2.z + v3.z);
        acc.w += (v0.w + v1.w) + (v2.w + v3.w);
    }
    for (; j < r1; j += 2) {
        int s = csr[j];
        float4 v = bf4(*(const ushort4*)(hWb + (size_t)s * 128 + c));
        acc.x += v.x; acc.y += v.y; acc.z += v.z; acc.w += v.w;
    }
    acc.x += __shfl_xor(acc.x, 32, 64);
    acc.y += __shfl_xor(acc.y, 32, 64);
    acc.z += __shfl_xor(acc.z, 32, 64);
    acc.w += __shfl_xor(acc.w, 32, 64);
    if (lane < 32) {
        float dd = dinv[d];
        float4 vd = bf4(*(const ushort4*)(hWb + (size_t)d * 128 + c));
        float4 bb = *(const float4*)(b + c);
        float4 o;
        o.x = fmaxf(fmaf(acc.x + vd.x, dd, bb.x), 0.f);
        o.y = fmaxf(fmaf(acc.y + vd.y, dd, bb.y), 0.f);
        o.z = fmaxf(fmaf(acc.z + vd.z, dd, bb.z), 0.f);
        o.w = fmaxf(fmaf(acc.w + vd.w, dd, bb.w), 0.f);
        *(float4*)(h1 + (size_t)d * 128 + c) = o;
        ushort4 p;
        p.x = f2bf(o.x); p.y = f2bf(o.y); p.z = f2bf(o.z); p.w = f2bf(o.w);
        *(ushort4*)(h1b + (size_t)d * 128 + c) = p;
    }
}

// SAGE gather over bf16 h1
__global__ __launch_bounds__(256)
void sage_gather(const int* __restrict__ rowptr, const int* __restrict__ csr,
                 const float* __restrict__ icnt,
                 const unsigned short* __restrict__ h1b,
                 float* __restrict__ mean, int n)
{
    int d = blockIdx.x * 4 + (threadIdx.x >> 6);
    if (d >= n) return;
    int lane = threadIdx.x & 63;
    int half = lane >> 5;
    int c = (lane & 31) << 2;
    int r0 = rowptr[d], r1 = rowptr[d + 1];
    float4 acc = make_float4(0.f, 0.f, 0.f, 0.f);
    int j = r0 + half;
    for (; j + 6 < r1; j += 8) {
        int s0 = csr[j], s1 = csr[j + 2], s2 = csr[j + 4], s3 = csr[j + 6];
        float4 v0 = bf4(*(const ushort4*)(h1b + (size_t)s0 * 128 + c));
        float4 v1 = bf4(*(const ushort4*)(h1b + (size_t)s1 * 128 + c));
        float4 v2 = bf4(*(const ushort4*)(h1b + (size_t)s2 * 128 + c));
        float4 v3 = bf4(*(const ushort4*)(h1b + (size_t)s3 * 128 + c));
        acc.x += (v0.x + v1.x) + (v2.x + v3.x);
        acc.y += (v0.y + v1.y) + (v2.y + v3.y);
        acc.z += (v0.z + v1.z) + (v2.z + v3.z);
        acc.w += (v0.w + v1.w) + (v2.w + v3.w);
    }
    for (; j < r1; j += 2) {
        int s = csr[j];
        float4 v = bf4(*(const ushort4*)(h1b + (size_t)s * 128 + c));
        acc.x += v.x; acc.y += v.y; acc.z += v.z; acc.w += v.w;
    }
    acc.x += __shfl_xor(acc.x, 32, 64);
    acc.y += __shfl_xor(acc.y, 32, 64);
    acc.z += __shfl_xor(acc.z, 32, 64);
    acc.w += __shfl_xor(acc.w, 32, 64);
    if (lane < 32) {
        float ic = icnt[d];
        float4 o;
        o.x = acc.x * ic; o.y = acc.y * ic; o.z = acc.z * ic; o.w = acc.w * ic;
        *(float4*)(mean + (size_t)d * 128 + c) = o;
    }
}

// ---------------------------------------------------------------------------
// GAT fused single pass, lane-parallel softmax weights (round 6).
__global__ __launch_bounds__(256)
void gat_gather(const int* __restrict__ rowptr, const int* __restrict__ csr,
                const float* __restrict__ a_s, const float* __restrict__ a_d,
                const unsigned short* __restrict__ xWb,
                const float* __restrict__ b_gat,
                const float* __restrict__ W_out, const float* __restrict__ b_out,
                float* __restrict__ out, int n)
{
    __shared__ float h3row[4][128];
    int wv = threadIdx.x >> 6;
    int d = blockIdx.x * 4 + wv;
    if (d >= n) return;
    int lane = threadIdx.x & 63;
    const int hoff = lane >> 5;
    const int hsel = lane & 32;
    int r0 = rowptr[d], r1 = rowptr[d + 1];
    const int nE = r1 - r0;
    const float adh = a_d[d * 2 + hoff];

    float4 acc = make_float4(0.f, 0.f, 0.f, 0.f);
    float wacc = 0.f;

    for (int blk = 0; blk < nE; blk += 32) {
        int eidx = blk + (lane & 31);
        int s_l = d;
        float wl = 0.f;
        if (eidx < nE) {
            s_l = csr[r0 + eidx];
            wl = __expf(leaky02(a_s[s_l * 2 + hoff] + adh));
        }
        wacc += wl;
        int cnt = min(32, nE - blk);
        int e = 0;
        for (; e + 4 <= cnt; e += 4) {
            int   s0 = __shfl(s_l, e + 0, 64), s1 = __shfl(s_l, e + 1, 64);
            int   s2 = __shfl(s_l, e + 2, 64), s3 = __shfl(s_l, e + 3, 64);
            float w0 = __shfl(wl, (e + 0) | hsel, 64);
            float w1 = __shfl(wl, (e + 1) | hsel, 64);
            float w2 = __shfl(wl, (e + 2) | hsel, 64);
            float w3 = __shfl(wl, (e + 3) | hsel, 64);
            float4 v0 = bf4(((const ushort4*)(xWb + (size_t)s0 * 256))[lane]);
            float4 v1 = bf4(((const ushort4*)(xWb + (size_t)s1 * 256))[lane]);
            float4 v2 = bf4(((const ushort4*)(xWb + (size_t)s2 * 256))[lane]);
            float4 v3 = bf4(((const ushort4*)(xWb + (size_t)s3 * 256))[lane]);
            acc.x = fmaf(v0.x, w0, fmaf(v1.x, w1, fmaf(v2.x, w2, fmaf(v3.x, w3, acc.x))));
            acc.y = fmaf(v0.y, w0, fmaf(v1.y, w1, fmaf(v2.y, w2, fmaf(v3.y, w3, acc.y))));
            acc.z = fmaf(v0.z, w0, fmaf(v1.z, w1, fmaf(v2.z, w2, fmaf(v3.z, w3, acc.z))));
            acc.w = fmaf(v0.w, w0, fmaf(v1.w, w1, fmaf(v2.w, w2, fmaf(v3.w, w3, acc.w))));
        }
        for (; e < cnt; ++e) {
            int   s = __shfl(s_l, e, 64);
            float w = __shfl(wl, e | hsel, 64);
            float4 v = bf4(((const ushort4*)(xWb + (size_t)s * 256))[lane]);
            acc.x = fmaf(v.x, w, acc.x);
            acc.y = fmaf(v.y, w, acc.y);
            acc.z = fmaf(v.z, w, acc.z);
            acc.w = fmaf(v.w, w, acc.w);
        }
    }

    float wself = __expf(leaky02(a_s[d * 2 + hoff] + adh));
    {
        float4 v = bf4(((const ushort4*)(xWb + (size_t)d * 256))[lane]);
        acc.x = fmaf(v.x, wself, acc.x);
        acc.y = fmaf(v.y, wself, acc.y);
        acc.z = fmaf(v.z, wself, acc.z);
        acc.w = fmaf(v.w, wself, acc.w);
    }
#pragma unroll
    for (int sh = 16; sh > 0; sh >>= 1) wacc += __shfl_xor(wacc, sh, 64);
    float inv = 1.f / (wacc + wself + 1e-16f);
    acc.x *= inv; acc.y *= inv; acc.z *= inv; acc.w *= inv;

    float c0 = acc.x + __shfl_xor(acc.x, 32, 64);
    float c1 = acc.y + __shfl_xor(acc.y, 32, 64);
    float c2 = acc.z + __shfl_xor(acc.z, 32, 64);
    float c3 = acc.w + __shfl_xor(acc.w, 32, 64);
    if (lane < 32) {
        float4 bb = ((const float4*)b_gat)[lane];
        float4 o;
        o.x = fmaxf(0.5f * c0 + bb.x, 0.f);
        o.y = fmaxf(0.5f * c1 + bb.y, 0.f);
        o.z = fmaxf(0.5f * c2 + bb.z, 0.f);
        o.w = fmaxf(0.5f * c3 + bb.w, 0.f);
        ((float4*)h3row[wv])[lane] = o;
    }
    __threadfence_block();
    const float* hr = h3row[wv];
    float t0 = 0.f, t1 = 0.f, t2 = 0.f, t3 = 0.f;
#pragma unroll 8
    for (int k = 0; k < 128; k += 4) {
        t0 = fmaf(hr[k + 0], W_out[(k + 0) * 64 + lane], t0);
        t1 = fmaf(hr[k + 1], W_out[(k + 1) * 64 + lane], t1);
        t2 = fmaf(hr[k + 2], W_out[(k + 2) * 64 + lane], t2);
        t3 = fmaf(hr[k + 3], W_out[(k + 3) * 64 + lane], t3);
    }
    out[(size_t)d * 64 + lane] = (t0 + t1) + (t2 + t3) + b_out[lane];
}

// ---------------------------------------------------------------------------
extern "C" void kernel_launch(void* const* d_in, const int* in_sizes, int n_in,
                              void* d_out, int out_size, void* d_ws, size_t ws_size,
                              hipStream_t stream)
{
    const float* x      = (const float*)d_in[0];
    const int*   ei     = (const int*)d_in[1];
    const int*   nidx   = (const int*)d_in[2];
    const float* emb    = (const float*)d_in[3];
    const float* W_gcn  = (const float*)d_in[4];
    const float* b_gcn  = (const float*)d_in[5];
    const float* W_sl   = (const float*)d_in[6];
    const float* W_sr   = (const float*)d_in[7];
    const float* b_sage = (const float*)d_in[8];
    const float* W_gat  = (const float*)d_in[9];
    const float* att_s  = (const float*)d_in[10];
    const float* att_d  = (const float*)d_in[11];
    const float* b_gat  = (const float*)d_in[12];
    const float* W_out  = (const float*)d_in[13];
    const float* b_out  = (const float*)d_in[14];
    float* out = (float*)d_out;

    const int n = in_sizes[0] / 128;
    const int E = in_sizes[1] / 2;
    const int* esrc = ei;
    const int* edst = ei + E;

    const size_t P = (size_t)n * 128;
    const int nb_scan = (n + 1023) / 1024;
    float* ws   = (float*)d_ws;
    float* mean = ws;                 // P fp32
    float* h1   = ws + P;             // P fp32
    float* h2   = ws + 2 * P;         // P fp32
    unsigned short* hWb = (unsigned short*)(ws + 3 * P);          // P bf16
    unsigned short* h1b = (unsigned short*)(ws + 3 * P + P / 2);  // P bf16
    unsigned short* xWb = (unsigned short*)(ws + 4 * P);          // 2P bf16
    float* dinv = ws + 5 * P;
    float* icnt = dinv + n;
    float* a_s  = icnt + n;
    float* a_d  = a_s + 2 * n;
    int* degi   = (int*)(a_d + 2 * n);
    int* fill   = degi + n;
    int* rowptr = fill + n;
    int* partial= rowptr + n + 1;
    int* csr    = partial + nb_scan + 1;

    const int TB = 256;
    int nblk_e     = (E + TB - 1) / TB;
    int nblk_wav_n = (n + 3) / 4;
    int gemm_rows  = (n + 127) / 128;

    // --- degrees + CSR build ---
    hipMemsetAsync(degi, 0, 2 * (size_t)n * sizeof(int), stream);
    deg_edges<<<nblk_e, TB, 0, stream>>>(edst, degi, E);
    scan_part_norm<<<nb_scan, TB, 0, stream>>>(degi, partial, dinv, icnt, n);
    scan_offsets<<<1, 64, 0, stream>>>(partial, nb_scan);
    scan_write<<<nb_scan, TB, 0, stream>>>(degi, partial, rowptr, n);
    csr_fill<<<nblk_e, TB, 0, stream>>>(esrc, edst, rowptr, fill, csr, E);

    // --- GCN: hWb = bf16( (x@Wg_top + emb@Wg_bot) * dinv[row] ) ---
    gemm_mfma<true, false, false, true, true, false, true>
        <<<dim3(gemm_rows, 1), TB, 0, stream>>>(
        x, W_gcn, emb, W_gcn + 128 * 128, nidx, nullptr, dinv,
        nullptr, nullptr, nullptr, nullptr, (float*)hWb, n, 128, 128);
    gcn_gather<<<nblk_wav_n, TB, 0, stream>>>(rowptr, csr, dinv, hWb, b_gcn,
                                              h1, h1b, n);

    // --- SAGE ---
    sage_gather<<<nblk_wav_n, TB, 0, stream>>>(rowptr, csr, icnt, h1b, mean, n);
    gemm_mfma<true, true, true, false, false, false, false>
        <<<dim3(gemm_rows, 1), TB, 0, stream>>>(
        mean, W_sl, h1, W_sr, nullptr, b_sage, nullptr,
        nullptr, nullptr, nullptr, nullptr, h2, n, 128, 128);

    // --- GAT: xWb (bf16) + fused attention logits ---
    gemm_mfma<false, false, false, false, false, true, true>
        <<<dim3(gemm_rows, 2), TB, 0, stream>>>(
        h2, W_gat, nullptr, nullptr, nullptr, nullptr, nullptr,
        att_s, att_d, a_s, a_d, (float*)xWb, n, 256, 256);
    gat_gather<<<nblk_wav_n, TB, 0, stream>>>(rowptr, csr, a_s, a_d, xWb, b_gat,
                                              W_out, b_out, out, n);
}